// Round 20
// baseline (191.490 us; speedup 1.0000x reference)
//
#include <hip/hip_runtime.h>
#include <cstdint>
#include <cstddef>

typedef _Float16 f16x8 __attribute__((ext_vector_type(8)));
typedef _Float16 f16x4 __attribute__((ext_vector_type(4)));
typedef float    f32x4 __attribute__((ext_vector_type(4)));
typedef unsigned u32;
typedef const u32 __attribute__((address_space(1)))* gas_ptr;
typedef u32 __attribute__((address_space(3)))* las_ptr;

#define MFMA16(a, b, c) __builtin_amdgcn_mfma_f32_16x16x32_f16((a), (b), (c), 0, 0, 0)

static constexpr int Bb   = 16;
static constexpr int Ss   = 1024;
static constexpr int HID  = 768;
static constexpr int Hh   = 12;
static constexpr int DH   = 64;
static constexpr int Mrows = Bb * Ss;     // 16384
static constexpr int N3    = 3 * HID;     // 2304

// Q prescale: 1/sqrt(DH) * log2(e)  -> scores come out in log2 domain, P = exp2(z)
static constexpr float QSCL  = 0.125f * 1.44269504088896f;   // 0.18033688
// phi_q reconstruction from stored Q: q/64^0.25 = Qstored * (0.35355339/0.18033688)
static constexpr float PHSCL = 1.9605161f;

// ---------------- prep: cast hs (f32->f16) + pack W + bias, one launch ----------------
__global__ void prep(const float* __restrict__ hs, _Float16* __restrict__ A16,
                     const float* __restrict__ Wq, const float* __restrict__ Wk,
                     const float* __restrict__ Wv, const float* __restrict__ bq,
                     const float* __restrict__ bk, const float* __restrict__ bv,
                     _Float16* __restrict__ Wt, float* __restrict__ bias) {
    const int i = blockIdx.x * 256 + threadIdx.x;
    if (i < Mrows * HID / 4) {
        float4 v = ((const float4*)hs)[i];
        f16x4 o;
        o[0] = (_Float16)v.x; o[1] = (_Float16)v.y;
        o[2] = (_Float16)v.z; o[3] = (_Float16)v.w;
        ((f16x4*)A16)[i] = o;
    }
    if (i < N3 * HID / 8) {
        const int i8 = i * 8;
        int n = i8 / HID;
        int k = i8 - n * HID;        // 8-aligned, 768%8==0 -> no row crossing
        int sel = n / HID;
        int nn  = n - sel * HID;
        const float* W = (sel == 0) ? Wq : (sel == 1) ? Wk : Wv;
        const float* wp = W + (size_t)nn * HID + k;
        float4 v0 = *(const float4*)wp;
        float4 v1 = *(const float4*)(wp + 4);
        uint4 o;
        o.x = __builtin_bit_cast(u32, __builtin_amdgcn_cvt_pkrtz(v0.x, v0.y));
        o.y = __builtin_bit_cast(u32, __builtin_amdgcn_cvt_pkrtz(v0.z, v0.w));
        o.z = __builtin_bit_cast(u32, __builtin_amdgcn_cvt_pkrtz(v1.x, v1.y));
        o.w = __builtin_bit_cast(u32, __builtin_amdgcn_cvt_pkrtz(v1.z, v1.w));
        *(uint4*)(Wt + i8) = o;
    }
    if (i < N3) {
        int wsel = i / HID, j = i - wsel * HID;
        bias[i] = (wsel == 0) ? bq[j] : (wsel == 1) ? bk[j] : bv[j];
    }
}

// ---------------- fused QKV projection GEMM v7: 256x128 tile, 512 threads (8 waves) ----------------
// Same verified template as v6 (BK=64, single-buffer, global_load_lds w16, pre-swizzled source,
// identical per-wave 64x64 geometry / swizzle / barrier pattern / epilogue index functions).
// Parameter change only: M-tile 128->256, waves 4->8 -> 3 blocks/CU x 24 waves (was ~2.4 x 10),
// hiding the per-K-step drain with resident-wave overlap; A-panel L2 reuse doubles.
__global__ __launch_bounds__(512, 2) void qkv_gemm(
    const _Float16* __restrict__ A, const _Float16* __restrict__ Bt,
    const float* __restrict__ bias,
    _Float16* __restrict__ Qo, _Float16* __restrict__ Ko, _Float16* __restrict__ VTo) {
    __shared__ _Float16 As[256 * 64];   // 32 KB
    __shared__ _Float16 Bs[128 * 64];   // 16 KB
    const int tid  = threadIdx.x;
    const int lane = tid & 63, wid = tid >> 6;      // 8 waves
    const int g = lane >> 4, c = lane & 15;
    const int bm = blockIdx.x & 63, bn = blockIdx.x >> 6;  // 64 x 18 blocks
    const int m0 = bm * 256, n0 = bn * 128;
    const int wm = wid >> 1, wn = wid & 1;          // 4 x 2 wave grid

    const int srk = ((lane & 7) ^ (lane >> 3)) << 3;   // pre-swizzled source k-offset (f16)

    f32x4 acc[4][4] = {};

    for (int kt = 0; kt < HID; kt += 64) {
        if (kt) __syncthreads();
        // A: 2048 x 16B chunks, 4 per thread; B: 1024 chunks, 2 per thread
#pragma unroll
        for (int i = 0; i < 4; ++i) {
            const int ch  = i * 512 + tid;
            const int row = ch >> 3;                // 0..255
            __builtin_amdgcn_global_load_lds(
                (gas_ptr)(A + (size_t)(m0 + row) * HID + kt + srk),
                (las_ptr)(As + ch * 8), 16, 0, 0);
        }
#pragma unroll
        for (int i = 0; i < 2; ++i) {
            const int ch  = i * 512 + tid;
            const int row = ch >> 3;                // 0..127
            __builtin_amdgcn_global_load_lds(
                (gas_ptr)(Bt + (size_t)(n0 + row) * HID + kt + srk),
                (las_ptr)(Bs + ch * 8), 16, 0, 0);
        }
        __syncthreads();

#pragma unroll
        for (int kk = 0; kk < 2; ++kk) {
            f16x8 af[4], bf[4];
#pragma unroll
            for (int mi = 0; mi < 4; ++mi) {
                const int row = wm * 64 + mi * 16 + c;
                af[mi] = *(const f16x8*)((const char*)As + row * 128 + ((((kk * 4 + g) ^ (c & 7))) << 4));
            }
#pragma unroll
            for (int ni = 0; ni < 4; ++ni) {
                const int row = wn * 64 + ni * 16 + c;
                bf[ni] = *(const f16x8*)((const char*)Bs + row * 128 + ((((kk * 4 + g) ^ (c & 7))) << 4));
            }
#pragma unroll
            for (int mi = 0; mi < 4; ++mi)
#pragma unroll
                for (int ni = 0; ni < 4; ++ni)
                    acc[mi][ni] = MFMA16(af[mi], bf[ni], acc[mi][ni]);
        }
    }

    // epilogue (verified): C/D layout row=g*4+r, col=c per 16x16 tile
#pragma unroll
    for (int ni = 0; ni < 4; ++ni) {
        const int col    = n0 + wn * 64 + ni * 16 + c;
        const int which  = col / HID;           // 0=q 1=k 2=v
        const int within = col - which * HID;
        const int hh = within >> 6, d = within & 63;
        const float bias_v = bias[col];
        const float scl = (which == 0) ? QSCL : 1.0f;
#pragma unroll
        for (int mi = 0; mi < 4; ++mi) {
            const int rowg0 = m0 + wm * 64 + mi * 16 + g * 4;
            const int bidx = rowg0 >> 10, s0 = rowg0 & 1023;
            const int bh   = bidx * Hh + hh;
            f16x4 hv4;
#pragma unroll
            for (int r = 0; r < 4; ++r)
                hv4[r] = (_Float16)((acc[mi][ni][r] + bias_v) * scl);
            if (which == 2) {
                // rho-permuted V^T store: u = mi*16+g*4+r -> p = 32(mi>>1)+8g+4(mi&1)+r
                const int base64 = (m0 + wm * 64) & 1023;
                const int p = 32 * (mi >> 1) + 8 * g + 4 * (mi & 1);
                *(uint2*)(VTo + ((size_t)bh * DH + d) * Ss + base64 + p) = __builtin_bit_cast(uint2, hv4);
            } else if (which == 0) {
#pragma unroll
                for (int r = 0; r < 4; ++r)
                    Qo[((size_t)bh * Ss + s0 + r) * DH + d] = hv4[r];
            } else {
#pragma unroll
                for (int r = 0; r < 4; ++r)
                    Ko[((size_t)bh * Ss + s0 + r) * DH + d] = hv4[r];
            }
        }
    }
}

// ---------------- flash attention v13 (verified round 19): pipelined exp/PV one tile behind QK ----------------
__global__ __launch_bounds__(256) void attn_kernel(
    const _Float16* __restrict__ Q, const _Float16* __restrict__ K,
    const _Float16* __restrict__ VT, const float* __restrict__ phi_k,
    const float* __restrict__ phi_kv, float* __restrict__ out) {
    __shared__ _Float16 Kb[2][64 * 64];     // XOR-swizzled [key][dh]
    __shared__ _Float16 Vb[3][64 * 64];     // XOR-swizzled [d][p-local], 3-ring

    const int tid  = threadIdx.x;
    const int lane = tid & 63, w = tid >> 6;
    const int g = lane >> 4, c = lane & 15;

    // XCD swizzle: 1536 blocks = 8 XCDs x 192; colocate same-bh blocks on one XCD
    const int wg = (blockIdx.x & 7) * 192 + (blockIdx.x >> 3);
    const int bh = wg >> 3, qt = wg & 7;
    const int b = bh / Hh, h = bh - b * Hh;
    const size_t base = (size_t)bh * Ss * DH;
    const _Float16* Kg = K + base;          // [1024][64]
    const _Float16* Vg = VT + base;         // [64][1024] (rho-permuted in s)

    const int srow = lane >> 3;                       // row within 8-row chunk (== row&7)
    const int scol = (((lane & 7) ^ srow) << 4) >> 1; // f16 col index, XOR on byte bits 4-6
    const int sw = (c & 7) << 4;

    // Q fragments (pre-scaled by QSCL at the GEMM): rows qt*128 + w*32 + mb*16 + c
    const _Float16* Qp = Q + base + (size_t)(qt * 128 + w * 32 + c) * DH + g * 8;
    f16x8 aq[2][2];
    aq[0][0] = *(const f16x8*)(Qp);
    aq[0][1] = *(const f16x8*)(Qp + 32);
    aq[1][0] = *(const f16x8*)(Qp + 16 * DH);
    aq[1][1] = *(const f16x8*)(Qp + 16 * DH + 32);

    float part[2] = {0.f, 0.f};     // per-lane partial of sum(e^s)
    f32x4 acco[2][4] = {};          // ctx^T: [mb][nd], lane holds q=c, d=nd*16+4g+r
    f32x4 zA[2][4], zB[2][4];       // pipelined score tiles (ping-pong, static names)

    auto stage = [&](int t) {
        const int t0 = t * 64;
        _Float16* kd = &Kb[t & 1][0];
        _Float16* vd = &Vb[t % 3][0];
#pragma unroll
        for (int i = 0; i < 2; ++i) {
            const int row0 = w * 16 + i * 8;
            __builtin_amdgcn_global_load_lds(
                (gas_ptr)(Kg + (size_t)(t0 + row0 + srow) * DH + scol),
                (las_ptr)(kd + row0 * 64), 16, 0, 0);
            __builtin_amdgcn_global_load_lds(
                (gas_ptr)(Vg + (size_t)(row0 + srow) * Ss + t0 + scol),
                (las_ptr)(vd + row0 * 64), 16, 0, 0);
        }
    };

    auto qk_phase = [&](int t, f32x4 (&zc)[2][4]) {
        const char* kb0 = (const char*)&Kb[t & 1][0];
        __builtin_amdgcn_s_setprio(1);
#pragma unroll
        for (int nt = 0; nt < 4; ++nt) {
            const char* kb = kb0 + (nt * 16 + c) * 128;
            f16x8 bk0 = *(const f16x8*)(kb + ((g * 16) ^ sw));
            f16x8 bk1 = *(const f16x8*)(kb + ((64 + g * 16) ^ sw));
            f32x4 z0 = {}, z1 = {};
            z0 = MFMA16(bk0, aq[0][0], z0);
            z0 = MFMA16(bk1, aq[0][1], z0);
            z1 = MFMA16(bk0, aq[1][0], z1);
            z1 = MFMA16(bk1, aq[1][1], z1);
            zc[0][nt] = z0;
            zc[1][nt] = z1;
        }
        __builtin_amdgcn_s_setprio(0);
    };

    auto exppv_phase = [&](int tp, f32x4 (&zp)[2][4]) {
        f16x8 pb[2][2];
#pragma unroll
        for (int j = 0; j < 2; ++j) {
#pragma unroll
            for (int kk = 0; kk < 2; ++kk) {
                float e0 = __builtin_amdgcn_exp2f(zp[j][2 * kk][0]);
                float e1 = __builtin_amdgcn_exp2f(zp[j][2 * kk][1]);
                float e2 = __builtin_amdgcn_exp2f(zp[j][2 * kk][2]);
                float e3 = __builtin_amdgcn_exp2f(zp[j][2 * kk][3]);
                float e4 = __builtin_amdgcn_exp2f(zp[j][2 * kk + 1][0]);
                float e5 = __builtin_amdgcn_exp2f(zp[j][2 * kk + 1][1]);
                float e6 = __builtin_amdgcn_exp2f(zp[j][2 * kk + 1][2]);
                float e7 = __builtin_amdgcn_exp2f(zp[j][2 * kk + 1][3]);
                part[j] += (e0 + e1 + e2 + e3) + (e4 + e5 + e6 + e7);
                uint4 pk;
                pk.x = __builtin_bit_cast(u32, __builtin_amdgcn_cvt_pkrtz(e0, e1));
                pk.y = __builtin_bit_cast(u32, __builtin_amdgcn_cvt_pkrtz(e2, e3));
                pk.z = __builtin_bit_cast(u32, __builtin_amdgcn_cvt_pkrtz(e4, e5));
                pk.w = __builtin_bit_cast(u32, __builtin_amdgcn_cvt_pkrtz(e6, e7));
                pb[j][kk] = __builtin_bit_cast(f16x8, pk);
            }
        }
        __builtin_amdgcn_s_setprio(1);
        const char* vb0 = (const char*)&Vb[tp % 3][0];
#pragma unroll
        for (int nd = 0; nd < 4; ++nd) {
            const char* vb = vb0 + (nd * 16 + c) * 128;
#pragma unroll
            for (int kk = 0; kk < 2; ++kk) {
                f16x8 va = *(const f16x8*)(vb + ((kk * 64 + g * 16) ^ sw));
                acco[0][nd] = MFMA16(va, pb[0][kk], acco[0][nd]);
                acco[1][nd] = MFMA16(va, pb[1][kk], acco[1][nd]);
            }
        }
        __builtin_amdgcn_s_setprio(0);
    };

    stage(0);
    stage(1);
    __syncthreads();        // tiles 0,1 landed
    qk_phase(0, zA);
    __syncthreads();        // seal Kb[0] reads before stage(2) overwrites it next iter

    for (int t = 1; t < 16; t += 2) {
        // odd sub-iteration: cur=zB, prev=zA
        if (t + 1 < 16) stage(t + 1);
        qk_phase(t, zB);
        exppv_phase(t - 1, zA);
        __syncthreads();
        if (t + 1 < 16) {
            // even sub-iteration: cur=zA, prev=zB
            if (t + 2 < 16) stage(t + 2);
            qk_phase(t + 1, zA);
            exppv_phase(t, zB);
            __syncthreads();
        }
    }
    exppv_phase(15, zB);    // drain the pipeline (V(15) in Vb[0], landed & sealed)

    // ---- epilogue: phi_q (sigma-ordered Q reload), normalizer, NTK correction ----
    const float* phk = phi_k + h * DH;
    const float* pkv = phi_kv + h * DH * DH;

    f16x8 pq2[2][2];     // phi_q packed with sigma k-map, per mb
    float invD[2];
#pragma unroll
    for (int mb = 0; mb < 2; ++mb) {
        const _Float16* Qr = Q + base + (size_t)(qt * 128 + w * 32 + mb * 16 + c) * DH;
        float dot = 0.f;
#pragma unroll
        for (int kk = 0; kk < 2; ++kk) {
            f16x4 qa = *(const f16x4*)(Qr + kk * 32 + 4 * g);
            f16x4 qb = *(const f16x4*)(Qr + kk * 32 + 16 + 4 * g);
            float4 fka = *(const float4*)(phk + kk * 32 + 4 * g);
            float4 fkb = *(const float4*)(phk + kk * 32 + 16 + 4 * g);
            const float fa[4] = {fka.x, fka.y, fka.z, fka.w};
            const float fb[4] = {fkb.x, fkb.y, fkb.z, fkb.w};
            f16x8 pq;
#pragma unroll
            for (int j = 0; j < 4; ++j) {
                float x0 = (float)qa[j] * PHSCL;    // q / 64^0.25
                float x1 = (float)qb[j] * PHSCL;
                float p0 = (x0 > 0.f) ? (x0 + 1.f) : __expf(x0);
                float p1 = (x1 > 0.f) ? (x1 + 1.f) : __expf(x1);
                dot += p0 * fabsf(fa[j]) + p1 * fabsf(fb[j]);
                pq[j]     = (_Float16)p0;
                pq[4 + j] = (_Float16)p1;
            }
            pq2[mb][kk] = pq;
        }
        dot += __shfl_xor(dot, 16);
        dot += __shfl_xor(dot, 32);
        float s = part[mb];
        s += __shfl_xor(s, 16);
        s += __shfl_xor(s, 32);
        invD[mb] = 1.f / (s + dot);
    }

    // correction MFMA (A = phi_kv^T with sigma k-map, shared across mb) + output
#pragma unroll
    for (int nd = 0; nd < 4; ++nd) {
        f16x8 fa[2];
#pragma unroll
        for (int kk = 0; kk < 2; ++kk) {
            f16x8 t;
#pragma unroll
            for (int j = 0; j < 8; ++j) {
                int dh = kk * 32 + 16 * (j >> 2) + 4 * g + (j & 3);
                t[j] = (_Float16)pkv[dh * DH + nd * 16 + c];
            }
            fa[kk] = t;
        }
#pragma unroll
        for (int mb = 0; mb < 2; ++mb) {
            f32x4 cc = {};
            cc = MFMA16(fa[0], pq2[mb][0], cc);
            cc = MFMA16(fa[1], pq2[mb][1], cc);
            f32x4 o = (acco[mb][nd] + cc) * invD[mb];
            const int srow_o = qt * 128 + w * 32 + mb * 16 + c;
            float* op = out + ((size_t)b * Ss + srow_o) * HID + h * DH + nd * 16 + 4 * g;
            *(f32x4*)op = o;
        }
    }
}

// ---------------- launch ----------------
extern "C" void kernel_launch(void* const* d_in, const int* in_sizes, int n_in,
                              void* d_out, int out_size, void* d_ws, size_t ws_size,
                              hipStream_t stream) {
    (void)in_sizes; (void)n_in; (void)out_size;
    const float* hs   = (const float*)d_in[0];
    const float* Wq   = (const float*)d_in[1];
    const float* bq   = (const float*)d_in[2];
    const float* Wk   = (const float*)d_in[3];
    const float* bk   = (const float*)d_in[4];
    const float* Wv   = (const float*)d_in[5];
    const float* bv   = (const float*)d_in[6];
    const float* phik = (const float*)d_in[7];
    const float* phikv= (const float*)d_in[8];
    float* out = (float*)d_out;

    char* ws = (char*)d_ws;
    constexpr size_t szA   = (size_t)Mrows * HID * 2;        // 25,165,824
    constexpr size_t szWt  = (size_t)N3 * HID * 2;           //  3,538,944
    constexpr size_t szBia = (size_t)N3 * 4;
    constexpr size_t szQ   = (size_t)Bb * Hh * Ss * DH * 2;  // 25,165,824
    _Float16* A16  = (_Float16*)(ws);
    _Float16* Wt   = (_Float16*)(ws + szA);
    float*    bias = (float*)(ws + szA + szWt);
    _Float16* Qb   = (_Float16*)(ws + szA + szWt + szBia);
    _Float16* Kb   = (_Float16*)(ws + szA + szWt + szBia + szQ);
    _Float16* VTb  = (_Float16*)(ws + szA + szWt + szBia + 2 * szQ);
    (void)ws_size;

    prep<<<(Mrows * HID / 4 + 255) / 256, 256, 0, stream>>>(hs, A16, Wq, Wk, Wv, bq, bk, bv, Wt, bias);
    qkv_gemm<<<dim3((Mrows / 256) * (N3 / 128)), 512, 0, stream>>>(A16, Wt, bias, Qb, Kb, VTb);
    attn_kernel<<<dim3(Bb * Hh * (Ss / 128)), 256, 0, stream>>>(Qb, Kb, VTb, phik, phikv, out);
}

// Round 21
// 174.559 us; speedup vs baseline: 1.0970x; 1.0970x over previous
//
#include <hip/hip_runtime.h>
#include <cstdint>
#include <cstddef>

typedef _Float16 f16x8 __attribute__((ext_vector_type(8)));
typedef _Float16 f16x4 __attribute__((ext_vector_type(4)));
typedef float    f32x4 __attribute__((ext_vector_type(4)));
typedef unsigned u32;
typedef const u32 __attribute__((address_space(1)))* gas_ptr;
typedef u32 __attribute__((address_space(3)))* las_ptr;

#define MFMA16(a, b, c) __builtin_amdgcn_mfma_f32_16x16x32_f16((a), (b), (c), 0, 0, 0)

static constexpr int Bb   = 16;
static constexpr int Ss   = 1024;
static constexpr int HID  = 768;
static constexpr int Hh   = 12;
static constexpr int DH   = 64;
static constexpr int Mrows = Bb * Ss;     // 16384
static constexpr int N3    = 3 * HID;     // 2304

// Q prescale: 1/sqrt(DH) * log2(e)  -> scores come out in log2 domain, P = exp2(z)
static constexpr float QSCL  = 0.125f * 1.44269504088896f;   // 0.18033688
// phi_q reconstruction from stored Q: q/64^0.25 = Qstored * (0.35355339/0.18033688)
static constexpr float PHSCL = 1.9605161f;

// ---------------- prep: cast hs (f32->f16) + pack W + bias, one launch ----------------
__global__ void prep(const float* __restrict__ hs, _Float16* __restrict__ A16,
                     const float* __restrict__ Wq, const float* __restrict__ Wk,
                     const float* __restrict__ Wv, const float* __restrict__ bq,
                     const float* __restrict__ bk, const float* __restrict__ bv,
                     _Float16* __restrict__ Wt, float* __restrict__ bias) {
    const int i = blockIdx.x * 256 + threadIdx.x;
    if (i < Mrows * HID / 4) {
        float4 v = ((const float4*)hs)[i];
        f16x4 o;
        o[0] = (_Float16)v.x; o[1] = (_Float16)v.y;
        o[2] = (_Float16)v.z; o[3] = (_Float16)v.w;
        ((f16x4*)A16)[i] = o;
    }
    if (i < N3 * HID / 8) {
        const int i8 = i * 8;
        int n = i8 / HID;
        int k = i8 - n * HID;        // 8-aligned, 768%8==0 -> no row crossing
        int sel = n / HID;
        int nn  = n - sel * HID;
        const float* W = (sel == 0) ? Wq : (sel == 1) ? Wk : Wv;
        const float* wp = W + (size_t)nn * HID + k;
        float4 v0 = *(const float4*)wp;
        float4 v1 = *(const float4*)(wp + 4);
        uint4 o;
        o.x = __builtin_bit_cast(u32, __builtin_amdgcn_cvt_pkrtz(v0.x, v0.y));
        o.y = __builtin_bit_cast(u32, __builtin_amdgcn_cvt_pkrtz(v0.z, v0.w));
        o.z = __builtin_bit_cast(u32, __builtin_amdgcn_cvt_pkrtz(v1.x, v1.y));
        o.w = __builtin_bit_cast(u32, __builtin_amdgcn_cvt_pkrtz(v1.z, v1.w));
        *(uint4*)(Wt + i8) = o;
    }
    if (i < N3) {
        int wsel = i / HID, j = i - wsel * HID;
        bias[i] = (wsel == 0) ? bq[j] : (wsel == 1) ? bk[j] : bv[j];
    }
}

// ---------------- Q/K projection GEMM: v6 loop + swapped MFMA + vectorized stores ----------------
// Columns 0..1535 (Q then K); which is block-uniform -> single orientation, no branch duplication.
// Swapped MFMA (r10-verified): lane holds 4 consecutive d at fixed s -> one uint2 store per quad.
__global__ __launch_bounds__(256, 2) void qkv_gemm_qk(
    const _Float16* __restrict__ A, const _Float16* __restrict__ Bt,
    const float* __restrict__ bias,
    _Float16* __restrict__ Qo, _Float16* __restrict__ Ko) {
    __shared__ _Float16 As[128 * 64];   // 16 KB
    __shared__ _Float16 Bs[128 * 64];   // 16 KB
    const int tid  = threadIdx.x;
    const int lane = tid & 63, wid = tid >> 6;
    const int g = lane >> 4, c = lane & 15;
    const int bm = blockIdx.x & 127, bn = blockIdx.x >> 7;  // 128 x 12 blocks
    const int m0 = bm * 128, n0 = bn * 128;
    const int wm = wid >> 1, wn = wid & 1;
    const int which = n0 / HID;     // 0=q 1=k (block-uniform)

    const int srk = ((lane & 7) ^ (lane >> 3)) << 3;   // pre-swizzled source k-offset (f16)

    f32x4 acc[4][4] = {};

    for (int kt = 0; kt < HID; kt += 64) {
        if (kt) __syncthreads();
#pragma unroll
        for (int i = 0; i < 4; ++i) {
            const int ch  = i * 256 + wid * 64 + lane;
            const int row = ch >> 3;
            __builtin_amdgcn_global_load_lds(
                (gas_ptr)(A + (size_t)(m0 + row) * HID + kt + srk),
                (las_ptr)(As + (i * 256 + wid * 64) * 8), 16, 0, 0);
            __builtin_amdgcn_global_load_lds(
                (gas_ptr)(Bt + (size_t)(n0 + row) * HID + kt + srk),
                (las_ptr)(Bs + (i * 256 + wid * 64) * 8), 16, 0, 0);
        }
        __syncthreads();

#pragma unroll
        for (int kk = 0; kk < 2; ++kk) {
            f16x8 af[4], bf[4];
#pragma unroll
            for (int mi = 0; mi < 4; ++mi) {
                const int row = wm * 64 + mi * 16 + c;
                af[mi] = *(const f16x8*)((const char*)As + row * 128 + ((((kk * 4 + g) ^ (c & 7))) << 4));
            }
#pragma unroll
            for (int ni = 0; ni < 4; ++ni) {
                const int row = wn * 64 + ni * 16 + c;
                bf[ni] = *(const f16x8*)((const char*)Bs + row * 128 + ((((kk * 4 + g) ^ (c & 7))) << 4));
            }
#pragma unroll
            for (int mi = 0; mi < 4; ++mi)
#pragma unroll
                for (int ni = 0; ni < 4; ++ni)
                    acc[mi][ni] = MFMA16(bf[ni], af[mi], acc[mi][ni]);   // D^T: [d][s]
        }
    }

    // epilogue (r10-verified): lane holds d = colbase+r (4 consecutive), s = ...+c
    _Float16* dst = (which == 0) ? Qo : Ko;
    const float scl = (which == 0) ? QSCL : 1.0f;
#pragma unroll
    for (int ni = 0; ni < 4; ++ni) {
        const int colbase = n0 + wn * 64 + ni * 16 + g * 4;
        const int within0 = colbase - which * HID;
        const int hh = within0 >> 6, d0 = within0 & 63;
        const float4 b4 = *(const float4*)(bias + colbase);
        const float bb[4] = {b4.x, b4.y, b4.z, b4.w};
#pragma unroll
        for (int mi = 0; mi < 4; ++mi) {
            const int s = m0 + wm * 64 + mi * 16 + c;
            const int bidx = s >> 10, sl = s & 1023;
            const int bh = bidx * Hh + hh;
            f16x4 hv4;
#pragma unroll
            for (int r = 0; r < 4; ++r)
                hv4[r] = (_Float16)((acc[mi][ni][r] + bb[r]) * scl);
            *(uint2*)(dst + ((size_t)bh * Ss + sl) * DH + d0) = __builtin_bit_cast(uint2, hv4);
        }
    }
}

// ---------------- V projection GEMM: v6 loop verbatim + rho-permuted V^T store ----------------
// Columns 1536..2303 (V only).
__global__ __launch_bounds__(256, 2) void qkv_gemm_v(
    const _Float16* __restrict__ A, const _Float16* __restrict__ Bt,
    const float* __restrict__ bias, _Float16* __restrict__ VTo) {
    __shared__ _Float16 As[128 * 64];   // 16 KB
    __shared__ _Float16 Bs[128 * 64];   // 16 KB
    const int tid  = threadIdx.x;
    const int lane = tid & 63, wid = tid >> 6;
    const int g = lane >> 4, c = lane & 15;
    const int bm = blockIdx.x & 127, bn = blockIdx.x >> 7;  // 128 x 6 blocks
    const int m0 = bm * 128, n0 = 2 * HID + bn * 128;
    const int wm = wid >> 1, wn = wid & 1;

    const int srk = ((lane & 7) ^ (lane >> 3)) << 3;   // pre-swizzled source k-offset (f16)

    f32x4 acc[4][4] = {};

    for (int kt = 0; kt < HID; kt += 64) {
        if (kt) __syncthreads();
#pragma unroll
        for (int i = 0; i < 4; ++i) {
            const int ch  = i * 256 + wid * 64 + lane;
            const int row = ch >> 3;
            __builtin_amdgcn_global_load_lds(
                (gas_ptr)(A + (size_t)(m0 + row) * HID + kt + srk),
                (las_ptr)(As + (i * 256 + wid * 64) * 8), 16, 0, 0);
            __builtin_amdgcn_global_load_lds(
                (gas_ptr)(Bt + (size_t)(n0 + row) * HID + kt + srk),
                (las_ptr)(Bs + (i * 256 + wid * 64) * 8), 16, 0, 0);
        }
        __syncthreads();

#pragma unroll
        for (int kk = 0; kk < 2; ++kk) {
            f16x8 af[4], bf[4];
#pragma unroll
            for (int mi = 0; mi < 4; ++mi) {
                const int row = wm * 64 + mi * 16 + c;
                af[mi] = *(const f16x8*)((const char*)As + row * 128 + ((((kk * 4 + g) ^ (c & 7))) << 4));
            }
#pragma unroll
            for (int ni = 0; ni < 4; ++ni) {
                const int row = wn * 64 + ni * 16 + c;
                bf[ni] = *(const f16x8*)((const char*)Bs + row * 128 + ((((kk * 4 + g) ^ (c & 7))) << 4));
            }
#pragma unroll
            for (int mi = 0; mi < 4; ++mi)
#pragma unroll
                for (int ni = 0; ni < 4; ++ni)
                    acc[mi][ni] = MFMA16(af[mi], bf[ni], acc[mi][ni]);   // D[s][d]
        }
    }

    // epilogue (v6/r13-verified V path): rho-permuted V^T uint2 store
#pragma unroll
    for (int ni = 0; ni < 4; ++ni) {
        const int col    = n0 + wn * 64 + ni * 16 + c;
        const int within = col - 2 * HID;
        const int hh = within >> 6, d = within & 63;
        const float bias_v = bias[col];
#pragma unroll
        for (int mi = 0; mi < 4; ++mi) {
            const int rowg0 = m0 + wm * 64 + mi * 16 + g * 4;
            const int bidx = rowg0 >> 10;
            const int bh   = bidx * Hh + hh;
            f16x4 hv4;
#pragma unroll
            for (int r = 0; r < 4; ++r)
                hv4[r] = (_Float16)(acc[mi][ni][r] + bias_v);
            const int base64 = (m0 + wm * 64) & 1023;
            const int p = 32 * (mi >> 1) + 8 * g + 4 * (mi & 1);
            *(uint2*)(VTo + ((size_t)bh * DH + d) * Ss + base64 + p) = __builtin_bit_cast(uint2, hv4);
        }
    }
}

// ---------------- flash attention v13 (verified round 19): pipelined exp/PV one tile behind QK ----------------
__global__ __launch_bounds__(256) void attn_kernel(
    const _Float16* __restrict__ Q, const _Float16* __restrict__ K,
    const _Float16* __restrict__ VT, const float* __restrict__ phi_k,
    const float* __restrict__ phi_kv, float* __restrict__ out) {
    __shared__ _Float16 Kb[2][64 * 64];     // XOR-swizzled [key][dh]
    __shared__ _Float16 Vb[3][64 * 64];     // XOR-swizzled [d][p-local], 3-ring

    const int tid  = threadIdx.x;
    const int lane = tid & 63, w = tid >> 6;
    const int g = lane >> 4, c = lane & 15;

    // XCD swizzle: 1536 blocks = 8 XCDs x 192; colocate same-bh blocks on one XCD
    const int wg = (blockIdx.x & 7) * 192 + (blockIdx.x >> 3);
    const int bh = wg >> 3, qt = wg & 7;
    const int b = bh / Hh, h = bh - b * Hh;
    const size_t base = (size_t)bh * Ss * DH;
    const _Float16* Kg = K + base;          // [1024][64]
    const _Float16* Vg = VT + base;         // [64][1024] (rho-permuted in s)

    const int srow = lane >> 3;                       // row within 8-row chunk (== row&7)
    const int scol = (((lane & 7) ^ srow) << 4) >> 1; // f16 col index, XOR on byte bits 4-6
    const int sw = (c & 7) << 4;

    // Q fragments (pre-scaled by QSCL at the GEMM): rows qt*128 + w*32 + mb*16 + c
    const _Float16* Qp = Q + base + (size_t)(qt * 128 + w * 32 + c) * DH + g * 8;
    f16x8 aq[2][2];
    aq[0][0] = *(const f16x8*)(Qp);
    aq[0][1] = *(const f16x8*)(Qp + 32);
    aq[1][0] = *(const f16x8*)(Qp + 16 * DH);
    aq[1][1] = *(const f16x8*)(Qp + 16 * DH + 32);

    float part[2] = {0.f, 0.f};     // per-lane partial of sum(e^s)
    f32x4 acco[2][4] = {};          // ctx^T: [mb][nd], lane holds q=c, d=nd*16+4g+r
    f32x4 zA[2][4], zB[2][4];       // pipelined score tiles (ping-pong, static names)

    auto stage = [&](int t) {
        const int t0 = t * 64;
        _Float16* kd = &Kb[t & 1][0];
        _Float16* vd = &Vb[t % 3][0];
#pragma unroll
        for (int i = 0; i < 2; ++i) {
            const int row0 = w * 16 + i * 8;
            __builtin_amdgcn_global_load_lds(
                (gas_ptr)(Kg + (size_t)(t0 + row0 + srow) * DH + scol),
                (las_ptr)(kd + row0 * 64), 16, 0, 0);
            __builtin_amdgcn_global_load_lds(
                (gas_ptr)(Vg + (size_t)(row0 + srow) * Ss + t0 + scol),
                (las_ptr)(vd + row0 * 64), 16, 0, 0);
        }
    };

    auto qk_phase = [&](int t, f32x4 (&zc)[2][4]) {
        const char* kb0 = (const char*)&Kb[t & 1][0];
        __builtin_amdgcn_s_setprio(1);
#pragma unroll
        for (int nt = 0; nt < 4; ++nt) {
            const char* kb = kb0 + (nt * 16 + c) * 128;
            f16x8 bk0 = *(const f16x8*)(kb + ((g * 16) ^ sw));
            f16x8 bk1 = *(const f16x8*)(kb + ((64 + g * 16) ^ sw));
            f32x4 z0 = {}, z1 = {};
            z0 = MFMA16(bk0, aq[0][0], z0);
            z0 = MFMA16(bk1, aq[0][1], z0);
            z1 = MFMA16(bk0, aq[1][0], z1);
            z1 = MFMA16(bk1, aq[1][1], z1);
            zc[0][nt] = z0;
            zc[1][nt] = z1;
        }
        __builtin_amdgcn_s_setprio(0);
    };

    auto exppv_phase = [&](int tp, f32x4 (&zp)[2][4]) {
        f16x8 pb[2][2];
#pragma unroll
        for (int j = 0; j < 2; ++j) {
#pragma unroll
            for (int kk = 0; kk < 2; ++kk) {
                float e0 = __builtin_amdgcn_exp2f(zp[j][2 * kk][0]);
                float e1 = __builtin_amdgcn_exp2f(zp[j][2 * kk][1]);
                float e2 = __builtin_amdgcn_exp2f(zp[j][2 * kk][2]);
                float e3 = __builtin_amdgcn_exp2f(zp[j][2 * kk][3]);
                float e4 = __builtin_amdgcn_exp2f(zp[j][2 * kk + 1][0]);
                float e5 = __builtin_amdgcn_exp2f(zp[j][2 * kk + 1][1]);
                float e6 = __builtin_amdgcn_exp2f(zp[j][2 * kk + 1][2]);
                float e7 = __builtin_amdgcn_exp2f(zp[j][2 * kk + 1][3]);
                part[j] += (e0 + e1 + e2 + e3) + (e4 + e5 + e6 + e7);
                uint4 pk;
                pk.x = __builtin_bit_cast(u32, __builtin_amdgcn_cvt_pkrtz(e0, e1));
                pk.y = __builtin_bit_cast(u32, __builtin_amdgcn_cvt_pkrtz(e2, e3));
                pk.z = __builtin_bit_cast(u32, __builtin_amdgcn_cvt_pkrtz(e4, e5));
                pk.w = __builtin_bit_cast(u32, __builtin_amdgcn_cvt_pkrtz(e6, e7));
                pb[j][kk] = __builtin_bit_cast(f16x8, pk);
            }
        }
        __builtin_amdgcn_s_setprio(1);
        const char* vb0 = (const char*)&Vb[tp % 3][0];
#pragma unroll
        for (int nd = 0; nd < 4; ++nd) {
            const char* vb = vb0 + (nd * 16 + c) * 128;
#pragma unroll
            for (int kk = 0; kk < 2; ++kk) {
                f16x8 va = *(const f16x8*)(vb + ((kk * 64 + g * 16) ^ sw));
                acco[0][nd] = MFMA16(va, pb[0][kk], acco[0][nd]);
                acco[1][nd] = MFMA16(va, pb[1][kk], acco[1][nd]);
            }
        }
        __builtin_amdgcn_s_setprio(0);
    };

    stage(0);
    stage(1);
    __syncthreads();        // tiles 0,1 landed
    qk_phase(0, zA);
    __syncthreads();        // seal Kb[0] reads before stage(2) overwrites it next iter

    for (int t = 1; t < 16; t += 2) {
        // odd sub-iteration: cur=zB, prev=zA
        if (t + 1 < 16) stage(t + 1);
        qk_phase(t, zB);
        exppv_phase(t - 1, zA);
        __syncthreads();
        if (t + 1 < 16) {
            // even sub-iteration: cur=zA, prev=zB
            if (t + 2 < 16) stage(t + 2);
            qk_phase(t + 1, zA);
            exppv_phase(t, zB);
            __syncthreads();
        }
    }
    exppv_phase(15, zB);    // drain the pipeline (V(15) in Vb[0], landed & sealed)

    // ---- epilogue: phi_q (sigma-ordered Q reload), normalizer, NTK correction ----
    const float* phk = phi_k + h * DH;
    const float* pkv = phi_kv + h * DH * DH;

    f16x8 pq2[2][2];     // phi_q packed with sigma k-map, per mb
    float invD[2];
#pragma unroll
    for (int mb = 0; mb < 2; ++mb) {
        const _Float16* Qr = Q + base + (size_t)(qt * 128 + w * 32 + mb * 16 + c) * DH;
        float dot = 0.f;
#pragma unroll
        for (int kk = 0; kk < 2; ++kk) {
            f16x4 qa = *(const f16x4*)(Qr + kk * 32 + 4 * g);
            f16x4 qb = *(const f16x4*)(Qr + kk * 32 + 16 + 4 * g);
            float4 fka = *(const float4*)(phk + kk * 32 + 4 * g);
            float4 fkb = *(const float4*)(phk + kk * 32 + 16 + 4 * g);
            const float fa[4] = {fka.x, fka.y, fka.z, fka.w};
            const float fb[4] = {fkb.x, fkb.y, fkb.z, fkb.w};
            f16x8 pq;
#pragma unroll
            for (int j = 0; j < 4; ++j) {
                float x0 = (float)qa[j] * PHSCL;    // q / 64^0.25
                float x1 = (float)qb[j] * PHSCL;
                float p0 = (x0 > 0.f) ? (x0 + 1.f) : __expf(x0);
                float p1 = (x1 > 0.f) ? (x1 + 1.f) : __expf(x1);
                dot += p0 * fabsf(fa[j]) + p1 * fabsf(fb[j]);
                pq[j]     = (_Float16)p0;
                pq[4 + j] = (_Float16)p1;
            }
            pq2[mb][kk] = pq;
        }
        dot += __shfl_xor(dot, 16);
        dot += __shfl_xor(dot, 32);
        float s = part[mb];
        s += __shfl_xor(s, 16);
        s += __shfl_xor(s, 32);
        invD[mb] = 1.f / (s + dot);
    }

    // correction MFMA (A = phi_kv^T with sigma k-map, shared across mb) + output
#pragma unroll
    for (int nd = 0; nd < 4; ++nd) {
        f16x8 fa[2];
#pragma unroll
        for (int kk = 0; kk < 2; ++kk) {
            f16x8 t;
#pragma unroll
            for (int j = 0; j < 8; ++j) {
                int dh = kk * 32 + 16 * (j >> 2) + 4 * g + (j & 3);
                t[j] = (_Float16)pkv[dh * DH + nd * 16 + c];
            }
            fa[kk] = t;
        }
#pragma unroll
        for (int mb = 0; mb < 2; ++mb) {
            f32x4 cc = {};
            cc = MFMA16(fa[0], pq2[mb][0], cc);
            cc = MFMA16(fa[1], pq2[mb][1], cc);
            f32x4 o = (acco[mb][nd] + cc) * invD[mb];
            const int srow_o = qt * 128 + w * 32 + mb * 16 + c;
            float* op = out + ((size_t)b * Ss + srow_o) * HID + h * DH + nd * 16 + 4 * g;
            *(f32x4*)op = o;
        }
    }
}

// ---------------- launch ----------------
extern "C" void kernel_launch(void* const* d_in, const int* in_sizes, int n_in,
                              void* d_out, int out_size, void* d_ws, size_t ws_size,
                              hipStream_t stream) {
    (void)in_sizes; (void)n_in; (void)out_size;
    const float* hs   = (const float*)d_in[0];
    const float* Wq   = (const float*)d_in[1];
    const float* bq   = (const float*)d_in[2];
    const float* Wk   = (const float*)d_in[3];
    const float* bk   = (const float*)d_in[4];
    const float* Wv   = (const float*)d_in[5];
    const float* bv   = (const float*)d_in[6];
    const float* phik = (const float*)d_in[7];
    const float* phikv= (const float*)d_in[8];
    float* out = (float*)d_out;

    char* ws = (char*)d_ws;
    constexpr size_t szA   = (size_t)Mrows * HID * 2;        // 25,165,824
    constexpr size_t szWt  = (size_t)N3 * HID * 2;           //  3,538,944
    constexpr size_t szBia = (size_t)N3 * 4;
    constexpr size_t szQ   = (size_t)Bb * Hh * Ss * DH * 2;  // 25,165,824
    _Float16* A16  = (_Float16*)(ws);
    _Float16* Wt   = (_Float16*)(ws + szA);
    float*    bias = (float*)(ws + szA + szWt);
    _Float16* Qb   = (_Float16*)(ws + szA + szWt + szBia);
    _Float16* Kb   = (_Float16*)(ws + szA + szWt + szBia + szQ);
    _Float16* VTb  = (_Float16*)(ws + szA + szWt + szBia + 2 * szQ);
    (void)ws_size;

    prep<<<(Mrows * HID / 4 + 255) / 256, 256, 0, stream>>>(hs, A16, Wq, Wk, Wv, bq, bk, bv, Wt, bias);
    qkv_gemm_qk<<<dim3((Mrows / 128) * 12), 256, 0, stream>>>(A16, Wt, bias, Qb, Kb);
    qkv_gemm_v<<<dim3((Mrows / 128) * 6), 256, 0, stream>>>(A16, Wt, bias, VTb);
    attn_kernel<<<dim3(Bb * Hh * (Ss / 128)), 256, 0, stream>>>(Qb, Kb, VTb, phik, phikv, out);
}

// Round 22
// 166.734 us; speedup vs baseline: 1.1485x; 1.0469x over previous
//
#include <hip/hip_runtime.h>
#include <cstdint>
#include <cstddef>

typedef _Float16 f16x8 __attribute__((ext_vector_type(8)));
typedef _Float16 f16x4 __attribute__((ext_vector_type(4)));
typedef float    f32x4 __attribute__((ext_vector_type(4)));
typedef unsigned u32;
typedef const u32 __attribute__((address_space(1)))* gas_ptr;
typedef u32 __attribute__((address_space(3)))* las_ptr;

#define MFMA16(a, b, c) __builtin_amdgcn_mfma_f32_16x16x32_f16((a), (b), (c), 0, 0, 0)

static constexpr int Bb   = 16;
static constexpr int Ss   = 1024;
static constexpr int HID  = 768;
static constexpr int Hh   = 12;
static constexpr int DH   = 64;
static constexpr int Mrows = Bb * Ss;     // 16384
static constexpr int N3    = 3 * HID;     // 2304

// Q prescale: 1/sqrt(DH) * log2(e)  -> scores come out in log2 domain, P = exp2(z)
static constexpr float QSCL  = 0.125f * 1.44269504088896f;   // 0.18033688
// phi_q reconstruction from stored Q: q/64^0.25 = Qstored * (0.35355339/0.18033688)
static constexpr float PHSCL = 1.9605161f;

// ---------------- prep: cast hs (f32->f16) + pack W + bias, one launch ----------------
__global__ void prep(const float* __restrict__ hs, _Float16* __restrict__ A16,
                     const float* __restrict__ Wq, const float* __restrict__ Wk,
                     const float* __restrict__ Wv, const float* __restrict__ bq,
                     const float* __restrict__ bk, const float* __restrict__ bv,
                     _Float16* __restrict__ Wt, float* __restrict__ bias) {
    const int i = blockIdx.x * 256 + threadIdx.x;
    if (i < Mrows * HID / 4) {
        float4 v = ((const float4*)hs)[i];
        f16x4 o;
        o[0] = (_Float16)v.x; o[1] = (_Float16)v.y;
        o[2] = (_Float16)v.z; o[3] = (_Float16)v.w;
        ((f16x4*)A16)[i] = o;
    }
    if (i < N3 * HID / 8) {
        const int i8 = i * 8;
        int n = i8 / HID;
        int k = i8 - n * HID;        // 8-aligned, 768%8==0 -> no row crossing
        int sel = n / HID;
        int nn  = n - sel * HID;
        const float* W = (sel == 0) ? Wq : (sel == 1) ? Wk : Wv;
        const float* wp = W + (size_t)nn * HID + k;
        float4 v0 = *(const float4*)wp;
        float4 v1 = *(const float4*)(wp + 4);
        uint4 o;
        o.x = __builtin_bit_cast(u32, __builtin_amdgcn_cvt_pkrtz(v0.x, v0.y));
        o.y = __builtin_bit_cast(u32, __builtin_amdgcn_cvt_pkrtz(v0.z, v0.w));
        o.z = __builtin_bit_cast(u32, __builtin_amdgcn_cvt_pkrtz(v1.x, v1.y));
        o.w = __builtin_bit_cast(u32, __builtin_amdgcn_cvt_pkrtz(v1.z, v1.w));
        *(uint4*)(Wt + i8) = o;
    }
    if (i < N3) {
        int wsel = i / HID, j = i - wsel * HID;
        bias[i] = (wsel == 0) ? bq[j] : (wsel == 1) ? bk[j] : bv[j];
    }
}

// ---------------- fused QKV projection GEMM v8: v6 loop + XCD-aware A-panel swizzle (T1) ----------------
// Identical compute/epilogue to verified v6 (round 13/19). Only the blockIdx->tile map changes:
// wgid = (idx&7)*288 + (idx>>3); bm = wgid/18; bn = wgid%18  (bijective: 2304 = 8*288).
// Each XCD runs contiguous bm-groups; the 18 blocks sharing an A-panel land on ONE XCD's L2.
__global__ __launch_bounds__(256, 2) void qkv_gemm(
    const _Float16* __restrict__ A, const _Float16* __restrict__ Bt,
    const float* __restrict__ bias,
    _Float16* __restrict__ Qo, _Float16* __restrict__ Ko, _Float16* __restrict__ VTo) {
    __shared__ _Float16 As[128 * 64];   // 16 KB
    __shared__ _Float16 Bs[128 * 64];   // 16 KB
    const int tid  = threadIdx.x;
    const int lane = tid & 63, wid = tid >> 6;
    const int g = lane >> 4, c = lane & 15;
    const int wgid = (blockIdx.x & 7) * 288 + (blockIdx.x >> 3);
    const int bm = wgid / 18, bn = wgid - bm * 18;
    const int m0 = bm * 128, n0 = bn * 128;
    const int wm = wid >> 1, wn = wid & 1;

    const int srk = ((lane & 7) ^ (lane >> 3)) << 3;   // pre-swizzled source k-offset (f16)

    f32x4 acc[4][4] = {};

    for (int kt = 0; kt < HID; kt += 64) {
        if (kt) __syncthreads();
#pragma unroll
        for (int i = 0; i < 4; ++i) {
            const int ch  = i * 256 + wid * 64 + lane;
            const int row = ch >> 3;
            __builtin_amdgcn_global_load_lds(
                (gas_ptr)(A + (size_t)(m0 + row) * HID + kt + srk),
                (las_ptr)(As + (i * 256 + wid * 64) * 8), 16, 0, 0);
            __builtin_amdgcn_global_load_lds(
                (gas_ptr)(Bt + (size_t)(n0 + row) * HID + kt + srk),
                (las_ptr)(Bs + (i * 256 + wid * 64) * 8), 16, 0, 0);
        }
        __syncthreads();

#pragma unroll
        for (int kk = 0; kk < 2; ++kk) {
            f16x8 af[4], bf[4];
#pragma unroll
            for (int mi = 0; mi < 4; ++mi) {
                const int row = wm * 64 + mi * 16 + c;
                af[mi] = *(const f16x8*)((const char*)As + row * 128 + ((((kk * 4 + g) ^ (c & 7))) << 4));
            }
#pragma unroll
            for (int ni = 0; ni < 4; ++ni) {
                const int row = wn * 64 + ni * 16 + c;
                bf[ni] = *(const f16x8*)((const char*)Bs + row * 128 + ((((kk * 4 + g) ^ (c & 7))) << 4));
            }
#pragma unroll
            for (int mi = 0; mi < 4; ++mi)
#pragma unroll
                for (int ni = 0; ni < 4; ++ni)
                    acc[mi][ni] = MFMA16(af[mi], bf[ni], acc[mi][ni]);
        }
    }

    // epilogue (verified): C/D layout row=g*4+r, col=c per 16x16 tile
#pragma unroll
    for (int ni = 0; ni < 4; ++ni) {
        const int col    = n0 + wn * 64 + ni * 16 + c;
        const int which  = col / HID;           // 0=q 1=k 2=v
        const int within = col - which * HID;
        const int hh = within >> 6, d = within & 63;
        const float bias_v = bias[col];
        const float scl = (which == 0) ? QSCL : 1.0f;
#pragma unroll
        for (int mi = 0; mi < 4; ++mi) {
            const int rowg0 = m0 + wm * 64 + mi * 16 + g * 4;
            const int bidx = rowg0 >> 10, s0 = rowg0 & 1023;
            const int bh   = bidx * Hh + hh;
            f16x4 hv4;
#pragma unroll
            for (int r = 0; r < 4; ++r)
                hv4[r] = (_Float16)((acc[mi][ni][r] + bias_v) * scl);
            if (which == 2) {
                // rho-permuted V^T store: u = mi*16+g*4+r -> p = 32(mi>>1)+8g+4(mi&1)+r
                const int base64 = (m0 + wm * 64) & 1023;
                const int p = 32 * (mi >> 1) + 8 * g + 4 * (mi & 1);
                *(uint2*)(VTo + ((size_t)bh * DH + d) * Ss + base64 + p) = __builtin_bit_cast(uint2, hv4);
            } else if (which == 0) {
#pragma unroll
                for (int r = 0; r < 4; ++r)
                    Qo[((size_t)bh * Ss + s0 + r) * DH + d] = hv4[r];
            } else {
#pragma unroll
                for (int r = 0; r < 4; ++r)
                    Ko[((size_t)bh * Ss + s0 + r) * DH + d] = hv4[r];
            }
        }
    }
}

// ---------------- flash attention v13 (verified round 19): pipelined exp/PV one tile behind QK ----------------
__global__ __launch_bounds__(256) void attn_kernel(
    const _Float16* __restrict__ Q, const _Float16* __restrict__ K,
    const _Float16* __restrict__ VT, const float* __restrict__ phi_k,
    const float* __restrict__ phi_kv, float* __restrict__ out) {
    __shared__ _Float16 Kb[2][64 * 64];     // XOR-swizzled [key][dh]
    __shared__ _Float16 Vb[3][64 * 64];     // XOR-swizzled [d][p-local], 3-ring

    const int tid  = threadIdx.x;
    const int lane = tid & 63, w = tid >> 6;
    const int g = lane >> 4, c = lane & 15;

    // XCD swizzle: 1536 blocks = 8 XCDs x 192; colocate same-bh blocks on one XCD
    const int wg = (blockIdx.x & 7) * 192 + (blockIdx.x >> 3);
    const int bh = wg >> 3, qt = wg & 7;
    const int b = bh / Hh, h = bh - b * Hh;
    const size_t base = (size_t)bh * Ss * DH;
    const _Float16* Kg = K + base;          // [1024][64]
    const _Float16* Vg = VT + base;         // [64][1024] (rho-permuted in s)

    const int srow = lane >> 3;                       // row within 8-row chunk (== row&7)
    const int scol = (((lane & 7) ^ srow) << 4) >> 1; // f16 col index, XOR on byte bits 4-6
    const int sw = (c & 7) << 4;

    // Q fragments (pre-scaled by QSCL at the GEMM): rows qt*128 + w*32 + mb*16 + c
    const _Float16* Qp = Q + base + (size_t)(qt * 128 + w * 32 + c) * DH + g * 8;
    f16x8 aq[2][2];
    aq[0][0] = *(const f16x8*)(Qp);
    aq[0][1] = *(const f16x8*)(Qp + 32);
    aq[1][0] = *(const f16x8*)(Qp + 16 * DH);
    aq[1][1] = *(const f16x8*)(Qp + 16 * DH + 32);

    float part[2] = {0.f, 0.f};     // per-lane partial of sum(e^s)
    f32x4 acco[2][4] = {};          // ctx^T: [mb][nd], lane holds q=c, d=nd*16+4g+r
    f32x4 zA[2][4], zB[2][4];       // pipelined score tiles (ping-pong, static names)

    auto stage = [&](int t) {
        const int t0 = t * 64;
        _Float16* kd = &Kb[t & 1][0];
        _Float16* vd = &Vb[t % 3][0];
#pragma unroll
        for (int i = 0; i < 2; ++i) {
            const int row0 = w * 16 + i * 8;
            __builtin_amdgcn_global_load_lds(
                (gas_ptr)(Kg + (size_t)(t0 + row0 + srow) * DH + scol),
                (las_ptr)(kd + row0 * 64), 16, 0, 0);
            __builtin_amdgcn_global_load_lds(
                (gas_ptr)(Vg + (size_t)(row0 + srow) * Ss + t0 + scol),
                (las_ptr)(vd + row0 * 64), 16, 0, 0);
        }
    };

    auto qk_phase = [&](int t, f32x4 (&zc)[2][4]) {
        const char* kb0 = (const char*)&Kb[t & 1][0];
        __builtin_amdgcn_s_setprio(1);
#pragma unroll
        for (int nt = 0; nt < 4; ++nt) {
            const char* kb = kb0 + (nt * 16 + c) * 128;
            f16x8 bk0 = *(const f16x8*)(kb + ((g * 16) ^ sw));
            f16x8 bk1 = *(const f16x8*)(kb + ((64 + g * 16) ^ sw));
            f32x4 z0 = {}, z1 = {};
            z0 = MFMA16(bk0, aq[0][0], z0);
            z0 = MFMA16(bk1, aq[0][1], z0);
            z1 = MFMA16(bk0, aq[1][0], z1);
            z1 = MFMA16(bk1, aq[1][1], z1);
            zc[0][nt] = z0;
            zc[1][nt] = z1;
        }
        __builtin_amdgcn_s_setprio(0);
    };

    auto exppv_phase = [&](int tp, f32x4 (&zp)[2][4]) {
        f16x8 pb[2][2];
#pragma unroll
        for (int j = 0; j < 2; ++j) {
#pragma unroll
            for (int kk = 0; kk < 2; ++kk) {
                float e0 = __builtin_amdgcn_exp2f(zp[j][2 * kk][0]);
                float e1 = __builtin_amdgcn_exp2f(zp[j][2 * kk][1]);
                float e2 = __builtin_amdgcn_exp2f(zp[j][2 * kk][2]);
                float e3 = __builtin_amdgcn_exp2f(zp[j][2 * kk][3]);
                float e4 = __builtin_amdgcn_exp2f(zp[j][2 * kk + 1][0]);
                float e5 = __builtin_amdgcn_exp2f(zp[j][2 * kk + 1][1]);
                float e6 = __builtin_amdgcn_exp2f(zp[j][2 * kk + 1][2]);
                float e7 = __builtin_amdgcn_exp2f(zp[j][2 * kk + 1][3]);
                part[j] += (e0 + e1 + e2 + e3) + (e4 + e5 + e6 + e7);
                uint4 pk;
                pk.x = __builtin_bit_cast(u32, __builtin_amdgcn_cvt_pkrtz(e0, e1));
                pk.y = __builtin_bit_cast(u32, __builtin_amdgcn_cvt_pkrtz(e2, e3));
                pk.z = __builtin_bit_cast(u32, __builtin_amdgcn_cvt_pkrtz(e4, e5));
                pk.w = __builtin_bit_cast(u32, __builtin_amdgcn_cvt_pkrtz(e6, e7));
                pb[j][kk] = __builtin_bit_cast(f16x8, pk);
            }
        }
        __builtin_amdgcn_s_setprio(1);
        const char* vb0 = (const char*)&Vb[tp % 3][0];
#pragma unroll
        for (int nd = 0; nd < 4; ++nd) {
            const char* vb = vb0 + (nd * 16 + c) * 128;
#pragma unroll
            for (int kk = 0; kk < 2; ++kk) {
                f16x8 va = *(const f16x8*)(vb + ((kk * 64 + g * 16) ^ sw));
                acco[0][nd] = MFMA16(va, pb[0][kk], acco[0][nd]);
                acco[1][nd] = MFMA16(va, pb[1][kk], acco[1][nd]);
            }
        }
        __builtin_amdgcn_s_setprio(0);
    };

    stage(0);
    stage(1);
    __syncthreads();        // tiles 0,1 landed
    qk_phase(0, zA);
    __syncthreads();        // seal Kb[0] reads before stage(2) overwrites it next iter

    for (int t = 1; t < 16; t += 2) {
        // odd sub-iteration: cur=zB, prev=zA
        if (t + 1 < 16) stage(t + 1);
        qk_phase(t, zB);
        exppv_phase(t - 1, zA);
        __syncthreads();
        if (t + 1 < 16) {
            // even sub-iteration: cur=zA, prev=zB
            if (t + 2 < 16) stage(t + 2);
            qk_phase(t + 1, zA);
            exppv_phase(t, zB);
            __syncthreads();
        }
    }
    exppv_phase(15, zB);    // drain the pipeline (V(15) in Vb[0], landed & sealed)

    // ---- epilogue: phi_q (sigma-ordered Q reload), normalizer, NTK correction ----
    const float* phk = phi_k + h * DH;
    const float* pkv = phi_kv + h * DH * DH;

    f16x8 pq2[2][2];     // phi_q packed with sigma k-map, per mb
    float invD[2];
#pragma unroll
    for (int mb = 0; mb < 2; ++mb) {
        const _Float16* Qr = Q + base + (size_t)(qt * 128 + w * 32 + mb * 16 + c) * DH;
        float dot = 0.f;
#pragma unroll
        for (int kk = 0; kk < 2; ++kk) {
            f16x4 qa = *(const f16x4*)(Qr + kk * 32 + 4 * g);
            f16x4 qb = *(const f16x4*)(Qr + kk * 32 + 16 + 4 * g);
            float4 fka = *(const float4*)(phk + kk * 32 + 4 * g);
            float4 fkb = *(const float4*)(phk + kk * 32 + 16 + 4 * g);
            const float fa[4] = {fka.x, fka.y, fka.z, fka.w};
            const float fb[4] = {fkb.x, fkb.y, fkb.z, fkb.w};
            f16x8 pq;
#pragma unroll
            for (int j = 0; j < 4; ++j) {
                float x0 = (float)qa[j] * PHSCL;    // q / 64^0.25
                float x1 = (float)qb[j] * PHSCL;
                float p0 = (x0 > 0.f) ? (x0 + 1.f) : __expf(x0);
                float p1 = (x1 > 0.f) ? (x1 + 1.f) : __expf(x1);
                dot += p0 * fabsf(fa[j]) + p1 * fabsf(fb[j]);
                pq[j]     = (_Float16)p0;
                pq[4 + j] = (_Float16)p1;
            }
            pq2[mb][kk] = pq;
        }
        dot += __shfl_xor(dot, 16);
        dot += __shfl_xor(dot, 32);
        float s = part[mb];
        s += __shfl_xor(s, 16);
        s += __shfl_xor(s, 32);
        invD[mb] = 1.f / (s + dot);
    }

    // correction MFMA (A = phi_kv^T with sigma k-map, shared across mb) + output
#pragma unroll
    for (int nd = 0; nd < 4; ++nd) {
        f16x8 fa[2];
#pragma unroll
        for (int kk = 0; kk < 2; ++kk) {
            f16x8 t;
#pragma unroll
            for (int j = 0; j < 8; ++j) {
                int dh = kk * 32 + 16 * (j >> 2) + 4 * g + (j & 3);
                t[j] = (_Float16)pkv[dh * DH + nd * 16 + c];
            }
            fa[kk] = t;
        }
#pragma unroll
        for (int mb = 0; mb < 2; ++mb) {
            f32x4 cc = {};
            cc = MFMA16(fa[0], pq2[mb][0], cc);
            cc = MFMA16(fa[1], pq2[mb][1], cc);
            f32x4 o = (acco[mb][nd] + cc) * invD[mb];
            const int srow_o = qt * 128 + w * 32 + mb * 16 + c;
            float* op = out + ((size_t)b * Ss + srow_o) * HID + h * DH + nd * 16 + 4 * g;
            *(f32x4*)op = o;
        }
    }
}

// ---------------- launch ----------------
extern "C" void kernel_launch(void* const* d_in, const int* in_sizes, int n_in,
                              void* d_out, int out_size, void* d_ws, size_t ws_size,
                              hipStream_t stream) {
    (void)in_sizes; (void)n_in; (void)out_size;
    const float* hs   = (const float*)d_in[0];
    const float* Wq   = (const float*)d_in[1];
    const float* bq   = (const float*)d_in[2];
    const float* Wk   = (const float*)d_in[3];
    const float* bk   = (const float*)d_in[4];
    const float* Wv   = (const float*)d_in[5];
    const float* bv   = (const float*)d_in[6];
    const float* phik = (const float*)d_in[7];
    const float* phikv= (const float*)d_in[8];
    float* out = (float*)d_out;

    char* ws = (char*)d_ws;
    constexpr size_t szA   = (size_t)Mrows * HID * 2;        // 25,165,824
    constexpr size_t szWt  = (size_t)N3 * HID * 2;           //  3,538,944
    constexpr size_t szBia = (size_t)N3 * 4;
    constexpr size_t szQ   = (size_t)Bb * Hh * Ss * DH * 2;  // 25,165,824
    _Float16* A16  = (_Float16*)(ws);
    _Float16* Wt   = (_Float16*)(ws + szA);
    float*    bias = (float*)(ws + szA + szWt);
    _Float16* Qb   = (_Float16*)(ws + szA + szWt + szBia);
    _Float16* Kb   = (_Float16*)(ws + szA + szWt + szBia + szQ);
    _Float16* VTb  = (_Float16*)(ws + szA + szWt + szBia + 2 * szQ);
    (void)ws_size;

    prep<<<(Mrows * HID / 4 + 255) / 256, 256, 0, stream>>>(hs, A16, Wq, Wk, Wv, bq, bk, bv, Wt, bias);
    qkv_gemm<<<dim3((Mrows / 128) * (N3 / 128)), 256, 0, stream>>>(A16, Wt, bias, Qb, Kb, VTb);
    attn_kernel<<<dim3(Bb * Hh * (Ss / 128)), 256, 0, stream>>>(Qb, Kb, VTb, phik, phikv, out);
}